// Round 1
// baseline (897.084 us; speedup 1.0000x reference)
//
#include <hip/hip_runtime.h>
#include <hip/hip_bf16.h>

// Problem constants
#define NN    8192
#define FEAT  64
#define HIDD  128
#define EMBD  128

typedef __bf16 bf16x8 __attribute__((ext_vector_type(8)));
typedef float  f32x4  __attribute__((ext_vector_type(4)));

// ---------------------------------------------------------------------------
// proj_pack: V_r = X @ W_r^T, stored as bf16 in MFMA B-fragment layout:
//   Vp[r][kb][n][lane][j],  kb = k/32 (256), n = col/16 (8), lane 0..63, j 0..7
//   element (lane,j) of fragment (kb,n) = V_r[kb*32 + (lane>>4)*8 + j][n*16 + (lane&15)]
// ---------------------------------------------------------------------------
template<int KIN>
__global__ __launch_bounds__(256) void proj_pack(
    const float* __restrict__ X, const float* __restrict__ W0,
    const float* __restrict__ W1, const float* __restrict__ W2,
    __bf16* __restrict__ Vp)
{
    size_t e = (size_t)blockIdx.x * 256 + threadIdx.x;   // < 3 * 2^20
    int j  = (int)(e & 7);
    int l  = (int)((e >> 3) & 63);
    int n  = (int)((e >> 9) & 7);
    int kb = (int)((e >> 12) & 255);
    int r  = (int)(e >> 20);
    int krow = kb * 32 + (l >> 4) * 8 + j;
    int col  = n * 16 + (l & 15);
    const float* w = (r == 0 ? W0 : (r == 1 ? W1 : W2)) + (size_t)col * KIN;
    const float* x = X + (size_t)krow * KIN;
    float s = 0.f;
#pragma unroll
    for (int t = 0; t < KIN; t += 4) {
        f32x4 xv = *(const f32x4*)(x + t);
        f32x4 wv = *(const f32x4*)(w + t);
        s += xv[0]*wv[0] + xv[1]*wv[1] + xv[2]*wv[2] + xv[3]*wv[3];
    }
    Vp[e] = (__bf16)s;
}

// ---------------------------------------------------------------------------
// gemm_AV: partial = A_r[rows, kchunk] @ V_r[kchunk, 128]
// block: 256 thr = 4 waves; wave = 32 rows x 128 cols; K-chunk = 2048
// grid: (64 Mtiles, 3 r, 4 chunks) = 768 blocks
// A loaded f32 -> cvt bf16 in regs; B from packed Vp (L2-resident). No LDS.
// ---------------------------------------------------------------------------
__global__ __launch_bounds__(256) void gemm_AV(
    const float* __restrict__ A0, const float* __restrict__ A1,
    const float* __restrict__ A2,
    const __bf16* __restrict__ Vp, float* __restrict__ P)
{
    const int mt = blockIdx.x;
    const int r  = blockIdx.y;
    const int ch = blockIdx.z;
    const float* A = (r == 0) ? A0 : (r == 1) ? A1 : A2;
    const int tid = threadIdx.x;
    const int w   = tid >> 6;
    const int l   = tid & 63;
    const int l15 = l & 15, l4 = l >> 4;
    const int rowbase = mt * 128 + w * 32;
    const int k0 = ch * 2048;

    f32x4 acc[2][8];
#pragma unroll
    for (int m = 0; m < 2; m++)
#pragma unroll
        for (int n = 0; n < 8; n++) acc[m][n] = (f32x4){0.f, 0.f, 0.f, 0.f};

    const __bf16* vpr = Vp + (size_t)r * (256 * 8 * 64 * 8);
    const float* arow0 = A + (size_t)(rowbase + l15) * NN + l4 * 8;
    const float* arow1 = A + (size_t)(rowbase + 16 + l15) * NN + l4 * 8;

    for (int kk = 0; kk < 2048; kk += 32) {
        const int kglob = k0 + kk;
        const int kb = kglob >> 5;
        bf16x8 afrag[2];
#pragma unroll
        for (int m = 0; m < 2; m++) {
            const float* ap = (m == 0 ? arow0 : arow1) + kglob;
            f32x4 lo = *(const f32x4*)ap;
            f32x4 hi = *(const f32x4*)(ap + 4);
            bf16x8 af;
            af[0] = (__bf16)lo[0]; af[1] = (__bf16)lo[1];
            af[2] = (__bf16)lo[2]; af[3] = (__bf16)lo[3];
            af[4] = (__bf16)hi[0]; af[5] = (__bf16)hi[1];
            af[6] = (__bf16)hi[2]; af[7] = (__bf16)hi[3];
            afrag[m] = af;
        }
        const __bf16* bp = vpr + (size_t)kb * 4096 + l * 8;
#pragma unroll
        for (int n = 0; n < 8; n++) {
            bf16x8 bfrag = *(const bf16x8*)(bp + n * 512);
            acc[0][n] = __builtin_amdgcn_mfma_f32_16x16x32_bf16(afrag[0], bfrag, acc[0][n], 0, 0, 0);
            acc[1][n] = __builtin_amdgcn_mfma_f32_16x16x32_bf16(afrag[1], bfrag, acc[1][n], 0, 0, 0);
        }
    }

    // C/D layout (verified m89/m91): col = lane&15, row = (lane>>4)*4 + i
    float* Pp = P + (size_t)(r * 4 + ch) * NN * 128;
#pragma unroll
    for (int m = 0; m < 2; m++)
#pragma unroll
        for (int n = 0; n < 8; n++) {
            int col = n * 16 + l15;
#pragma unroll
            for (int i = 0; i < 4; i++) {
                int row = rowbase + m * 16 + l4 * 4 + i;
                Pp[(size_t)row * 128 + col] = acc[m][n][i];
            }
        }
}

// ---------------------------------------------------------------------------
// reduce kernels: sum 12 partials + bias (+relu)
// ---------------------------------------------------------------------------
__global__ __launch_bounds__(256) void reduce_relu(
    const float* __restrict__ P, const float* __restrict__ bias,
    float* __restrict__ Hout)
{
    size_t idx = (size_t)blockIdx.x * 256 + threadIdx.x;   // < 2^20
    float s = bias[idx & 127];
#pragma unroll
    for (int p = 0; p < 12; p++) s += P[(size_t)p * (NN * 128) + idx];
    Hout[idx] = s > 0.f ? s : 0.f;
}

__global__ __launch_bounds__(256) void reduce_z(
    const float* __restrict__ P, const float* __restrict__ bias,
    float* __restrict__ Zout, __bf16* __restrict__ Zb)
{
    size_t idx = (size_t)blockIdx.x * 256 + threadIdx.x;
    float s = bias[idx & 127];
#pragma unroll
    for (int p = 0; p < 12; p++) s += P[(size_t)p * (NN * 128) + idx];
    Zout[idx] = s;
    Zb[idx]   = (__bf16)s;
}

// ---------------------------------------------------------------------------
// zzt: A_hat = Z @ Z^T, K=128, from row-major bf16 Z (2 MB, cache-resident)
// block: 4 waves, 128x128 tile; grid 64x64. Write-bound (268 MB).
// ---------------------------------------------------------------------------
__global__ __launch_bounds__(256) void zzt(
    const __bf16* __restrict__ Zb, float* __restrict__ Out)
{
    const int bx = blockIdx.x;   // col tile
    const int by = blockIdx.y;   // row tile
    const int tid = threadIdx.x;
    const int w = tid >> 6, l = tid & 63;
    const int l15 = l & 15, l4 = l >> 4;
    const int rowbase = by * 128 + w * 32;
    const int colbase = bx * 128;

    f32x4 acc[2][8];
#pragma unroll
    for (int m = 0; m < 2; m++)
#pragma unroll
        for (int n = 0; n < 8; n++) acc[m][n] = (f32x4){0.f, 0.f, 0.f, 0.f};

#pragma unroll
    for (int ks = 0; ks < 128; ks += 32) {
        bf16x8 af[2];
#pragma unroll
        for (int m = 0; m < 2; m++)
            af[m] = *(const bf16x8*)(Zb + (size_t)(rowbase + m * 16 + l15) * 128 + ks + l4 * 8);
#pragma unroll
        for (int n = 0; n < 8; n++) {
            bf16x8 bfr = *(const bf16x8*)(Zb + (size_t)(colbase + n * 16 + l15) * 128 + ks + l4 * 8);
            acc[0][n] = __builtin_amdgcn_mfma_f32_16x16x32_bf16(af[0], bfr, acc[0][n], 0, 0, 0);
            acc[1][n] = __builtin_amdgcn_mfma_f32_16x16x32_bf16(af[1], bfr, acc[1][n], 0, 0, 0);
        }
    }

#pragma unroll
    for (int m = 0; m < 2; m++)
#pragma unroll
        for (int n = 0; n < 8; n++) {
            int col = colbase + n * 16 + l15;
#pragma unroll
            for (int i = 0; i < 4; i++) {
                int row = rowbase + m * 16 + l4 * 4 + i;
                Out[(size_t)row * NN + col] = acc[m][n][i];
            }
        }
}

// ---------------------------------------------------------------------------
extern "C" void kernel_launch(void* const* d_in, const int* in_sizes, int n_in,
                              void* d_out, int out_size, void* d_ws, size_t ws_size,
                              hipStream_t stream)
{
    // setup_inputs() insertion order: H, A_buys, A_views, A_rates,
    //   W1_0, W2_0, W1_1, W2_1, W1_2, W2_2, b1, b2   (W1/W2 interleaved!)
    const float* H    = (const float*)d_in[0];
    const float* A0   = (const float*)d_in[1];
    const float* A1   = (const float*)d_in[2];
    const float* A2   = (const float*)d_in[3];
    const float* W1_0 = (const float*)d_in[4];
    const float* W2_0 = (const float*)d_in[5];
    const float* W1_1 = (const float*)d_in[6];
    const float* W2_1 = (const float*)d_in[7];
    const float* W1_2 = (const float*)d_in[8];
    const float* W2_2 = (const float*)d_in[9];
    const float* b1   = (const float*)d_in[10];
    const float* b2   = (const float*)d_in[11];

    float* Zout = (float*)d_out;                    // [8192][128]
    float* Ahat = (float*)d_out + (size_t)NN * EMBD; // [8192][8192]

    char* ws = (char*)d_ws;
    __bf16* Vp = (__bf16*)ws;                        //  6 MB packed V
    float*  P  = (float*)(ws + ((size_t)6  << 20));  // 48 MB partials (12 slabs)
    float*  H1 = (float*)(ws + ((size_t)54 << 20));  //  4 MB
    __bf16* Zb = (__bf16*)(ws + ((size_t)58 << 20)); //  2 MB

    // Layer 1
    proj_pack<FEAT><<<12288, 256, 0, stream>>>(H, W1_0, W1_1, W1_2, Vp);
    gemm_AV<<<dim3(64, 3, 4), 256, 0, stream>>>(A0, A1, A2, Vp, P);
    reduce_relu<<<4096, 256, 0, stream>>>(P, b1, H1);

    // Layer 2
    proj_pack<HIDD><<<12288, 256, 0, stream>>>(H1, W2_0, W2_1, W2_2, Vp);
    gemm_AV<<<dim3(64, 3, 4), 256, 0, stream>>>(A0, A1, A2, Vp, P);
    reduce_z<<<4096, 256, 0, stream>>>(P, b2, Zout, Zb);

    // Decoder
    zzt<<<dim3(64, 64), 256, 0, stream>>>(Zb, Ahat);
}